// Round 7
// baseline (121.647 us; speedup 1.0000x reference)
//
#include <hip/hip_runtime.h>
#include <hip/hip_bf16.h>

#define B_   8
#define N_   10000
#define H_   128
#define DIN_ 256
#define E_   160000
#define EPAD_ (E_ + 7 * N_ + 8)   // padded CSR capacity (each bucket rounded to x8)

typedef unsigned int uint_;
typedef unsigned short ushort_;
typedef __attribute__((ext_vector_type(8))) short short8;
typedef __attribute__((ext_vector_type(4))) float f32x4;

__device__ __forceinline__ float sigmoidf_(float v) { return 1.f / (1.f + __expf(-v)); }
// tanh via exp, safe at +/-inf
__device__ __forceinline__ float tanh_fast(float v) { float e = __expf(2.f * v); return 1.f - 2.f / (e + 1.f); }

__device__ __forceinline__ ushort_ f2bf(float f) {
    union { float f; uint_ u; } v; v.f = f;
    uint_ r = v.u + 0x7fff + ((v.u >> 16) & 1);   // round-to-nearest-even
    return (ushort_)(r >> 16);
}
#define BF_LO(u) __uint_as_float((u) << 16)
#define BF_HI(u) __uint_as_float((u) & 0xffff0000u)

// ---- degrees ------------------------------------------------------------
__global__ __launch_bounds__(256) void degrees_k(const int* __restrict__ src, const int* __restrict__ dst,
                                                 int* __restrict__ out_deg, int* __restrict__ in_deg) {
    int e = blockIdx.x * 256 + threadIdx.x;
    if (e < E_) {
        atomicAdd(&out_deg[src[e]], 1);
        atomicAdd(&in_deg[dst[e]], 1);
    }
}

// ---- norms + exclusive scan of PADDED in_deg -> CSR row offsets ---------
// Buckets padded to x8 so agg's edge walk needs no bounds logic (pad slots
// are zero-filled by the memset: src=0, coef=0 -> FMA no-op).
__global__ __launch_bounds__(1024) void norms_scan_k(const int* __restrict__ out_deg, const int* __restrict__ in_deg,
                                                     float* __restrict__ norm_out, float* __restrict__ norm_in,
                                                     int* __restrict__ offsets) {
    __shared__ int buf[10240];       // 40 KB
    __shared__ int part[1024];
    const int tid = threadIdx.x;
    // phase A: coalesced load of in_deg into LDS (padded) + coalesced norm writes
    #pragma unroll
    for (int q = 0; q < 10; ++q) {
        int idx = q * 1024 + tid;
        int d = (idx < N_) ? in_deg[idx] : 0;
        buf[idx] = (idx < N_) ? ((d + 7) & ~7) : 0;
        if (idx < N_) {
            int od = out_deg[idx];
            norm_out[idx] = od > 0 ? rsqrtf((float)od) : 0.f;
            norm_in[idx]  = d  > 0 ? rsqrtf((float)d)  : 0.f;
        }
    }
    __syncthreads();
    // phase B: per-thread scan of its contiguous 10-chunk (from LDS)
    int local[10];
    int s = 0;
    #pragma unroll
    for (int q = 0; q < 10; ++q) {
        local[q] = s;
        s += buf[tid * 10 + q];
    }
    part[tid] = s;
    __syncthreads();
    // phase C: block scan of partials
    for (int off = 1; off < 1024; off <<= 1) {
        int v = (tid >= off) ? part[tid - off] : 0;
        __syncthreads();
        part[tid] += v;
        __syncthreads();
    }
    int pre = (tid > 0) ? part[tid - 1] : 0;
    // phase D: write results into LDS, then coalesced store
    #pragma unroll
    for (int q = 0; q < 10; ++q)
        buf[tid * 10 + q] = pre + local[q];
    __syncthreads();
    #pragma unroll
    for (int q = 0; q < 10; ++q) {
        int idx = q * 1024 + tid;
        if (idx < N_) offsets[idx] = buf[idx];
    }
    if (tid == 1023) offsets[N_] = part[1023];
}

// ---- bucket-fill CSR: packed (src, coef) pairs --------------------------
__global__ __launch_bounds__(256) void fill_csr_k(const int* __restrict__ src, const int* __restrict__ dst,
                                                  const int* __restrict__ offsets, int* __restrict__ cursor,
                                                  const float* __restrict__ norm_out,
                                                  int2* __restrict__ csr_ed) {
    int e = blockIdx.x * 256 + threadIdx.x;
    if (e < E_) {
        int d = dst[e];
        int s = src[e];
        int pos = offsets[d] + atomicAdd(&cursor[d], 1);
        csr_ed[pos] = make_int2(s, __float_as_int(norm_out[s]));
    }
}

// ---- x projections + W^T cast: grid (4, 8); g==3 does wt transpose ------
__global__ __launch_bounds__(256) void xproj_k(const float* __restrict__ x,
                                               const float* __restrict__ w_r, const float* __restrict__ b_r,
                                               const float* __restrict__ w_z, const float* __restrict__ b_z,
                                               const float* __restrict__ w_h, const float* __restrict__ b_h,
                                               const float* __restrict__ gcn_w, ushort_* __restrict__ wt,
                                               float* __restrict__ xr, float* __restrict__ xz, float* __restrict__ xh) {
    const int g = blockIdx.x, b = blockIdx.y;
    if (g == 3) {                    // transpose + cast gcn_w (k,n) -> WT (n,k) bf16
        if (b != 0) return;
        const int t = threadIdx.x;
        const int n = t >> 1;
        const int kb = (t & 1) * 64;
        #pragma unroll
        for (int i = 0; i < 8; ++i) {
            int k = kb + i * 8;
            uint4 o;
            o.x = (uint_)f2bf(gcn_w[(k + 0) * H_ + n]) | ((uint_)f2bf(gcn_w[(k + 1) * H_ + n]) << 16);
            o.y = (uint_)f2bf(gcn_w[(k + 2) * H_ + n]) | ((uint_)f2bf(gcn_w[(k + 3) * H_ + n]) << 16);
            o.z = (uint_)f2bf(gcn_w[(k + 4) * H_ + n]) | ((uint_)f2bf(gcn_w[(k + 5) * H_ + n]) << 16);
            o.w = (uint_)f2bf(gcn_w[(k + 6) * H_ + n]) | ((uint_)f2bf(gcn_w[(k + 7) * H_ + n]) << 16);
            *(uint4*)(wt + n * H_ + k) = o;
        }
        return;
    }
    const float* __restrict__ w  = g == 0 ? w_r : (g == 1 ? w_z : w_h);
    const float* __restrict__ bs = g == 0 ? b_r : (g == 1 ? b_z : b_h);
    float* __restrict__ o        = g == 0 ? xr  : (g == 1 ? xz  : xh);
    const int k = threadIdx.x & 127, half = threadIdx.x >> 7;
    const float* xb = x + b * DIN_;
    float a = 0.f;
    #pragma unroll 8
    for (int d = half * 128; d < half * 128 + 128; ++d)
        a += xb[d] * w[d * H_ + k];
    __shared__ float part[2][128];
    part[half][k] = a;
    __syncthreads();
    if (half == 0) o[b * H_ + k] = a + part[1][k] + bs[k];
}

// ---- GEMM-first: hw = bf16(h_prev @ gcn_w) ------------------------------
// B-IN-REGISTERS: wt (128x128 bf16) is tile-invariant -> each of 8 waves
// holds its 16 B-fragments (64 VGPR) across all tiles; zero B ds_reads.
// 512 threads: wave w -> row-group (w>>1)*16, col-half (w&1)*64.
// LDS: A_s (stage, 16KB) + C_s (output transpose, 16KB). 2 barriers/tile.
// Grid (8, 79): blockIdx.x = batch == XCD (hw slab written where agg reads
// it); each block loops 2 tiles (t, t+79).
__global__ __launch_bounds__(512, 3) void gemm_cast_k(const float* __restrict__ h,
                                                      const ushort_* __restrict__ wt,
                                                      ushort_* __restrict__ hw) {
    __shared__ ushort_ A_s[64 * H_];    // [row][k] bf16, swizzled: 16 KB
    __shared__ ushort_ C_s[64 * H_];    // output transpose: 16 KB
    const int tid = threadIdx.x;
    const int b = blockIdx.x;           // batch (0..7) == XCD
    const size_t bslab = (size_t)b * N_;

    const int l  = tid & 63;
    const int w  = tid >> 6;            // wave 0..7
    const int rg = w >> 1;              // row-group (16 rows)
    const int ch = w & 1;               // col-half (64 cols)
    const int lr = l & 15;
    const int kg = (l >> 4) * 8;        // k-offset within 32-chunk
    const int arow = rg * 16 + lr;

    // B-fragments, held in registers for the whole kernel (16 x short8)
    short8 breg[4][4];
    #pragma unroll
    for (int kk = 0; kk < 4; ++kk)
        #pragma unroll
        for (int nf = 0; nf < 4; ++nf)
            breg[kk][nf] = *(const short8*)&wt[(ch * 64 + nf * 16 + lr) * H_ + kk * 32 + kg];

    for (int t = blockIdx.y; t < 157; t += 79) {    // tiles 0..156
        const int n0 = t * 64;
        // stage A: 64x128 fp32 -> bf16 LDS, swizzled (4 float4 per thread)
        #pragma unroll
        for (int i = 0; i < 4; ++i) {
            int f4 = i * 512 + tid;           // 0..2047
            int row = f4 >> 5;
            int col4 = (f4 & 31) * 4;
            f32x4 v = {0.f, 0.f, 0.f, 0.f};
            if (n0 + row < N_) v = *(const f32x4*)&h[(bslab + n0 + row) * H_ + col4];
            uint2 p;
            p.x = (uint_)f2bf(v[0]) | ((uint_)f2bf(v[1]) << 16);
            p.y = (uint_)f2bf(v[2]) | ((uint_)f2bf(v[3]) << 16);
            *(uint2*)&A_s[row * H_ + (col4 ^ ((row & 7) << 3))] = p;
        }
        __syncthreads();

        f32x4 acc[4];
        #pragma unroll
        for (int nf = 0; nf < 4; ++nf) acc[nf] = (f32x4){0.f, 0.f, 0.f, 0.f};

        #pragma unroll
        for (int kk = 0; kk < 4; ++kk) {
            int kus = kk * 32 + kg;
            short8 av = *(const short8*)&A_s[arow * H_ + (kus ^ ((arow & 7) << 3))];
            #pragma unroll
            for (int nf = 0; nf < 4; ++nf)
                acc[nf] = __builtin_amdgcn_mfma_f32_16x16x32_bf16(av, breg[kk][nf], acc[nf], 0, 0, 0);
        }

        // epilogue: C/D layout col = lane&15, row = (lane>>4)*4 + r (m89).
        // Scatter into C_s (swizzled), then coalesced read-back + store.
        const int wrow0 = rg * 16 + (l >> 4) * 4;
        #pragma unroll
        for (int nf = 0; nf < 4; ++nf) {
            int col = ch * 64 + nf * 16 + lr;
            #pragma unroll
            for (int r = 0; r < 4; ++r) {
                int row = wrow0 + r;
                C_s[row * H_ + (col ^ ((row & 7) << 3))] = f2bf(acc[nf][r]);
            }
        }
        __syncthreads();
        {
            int row = tid >> 3;               // 64 rows, 8 threads/row
            int c0 = (tid & 7) * 16;          // 16 ushorts = 32B per thread
            int swz = (row & 7) << 3;
            if (n0 + row < N_) {
                uint4 o0 = *(const uint4*)&C_s[row * H_ + ((c0 + 0) ^ swz)];
                uint4 o1 = *(const uint4*)&C_s[row * H_ + ((c0 + 8) ^ swz)];
                uint4* dst = (uint4*)(hw + (bslab + n0 + row) * (size_t)H_ + c0);
                dst[0] = o0; dst[1] = o1;
            }
        }
        // next stage-A write to A_s only happens after the barrier at the
        // top of the next iteration's __syncthreads? -> need one here to
        // protect C_s (read above) from next tile's scatter and A_s reads
        // are already done pre-barrier. One barrier suffices:
        __syncthreads();
    }
}

#define PROC_(E)                                                  \
    {                                                             \
        int   s_ = __builtin_amdgcn_readfirstlane((E).x);         \
        float c_ = __uint_as_float((uint_)(E).y);                 \
        uint_ u_ = *(const uint_*)(hb + (size_t)s_ * H_);         \
        a0 += c_ * BF_LO(u_);                                     \
        a1 += c_ * BF_HI(u_);                                     \
    }

// ---- aggregation of hw + fused GRU, one batch per XCD -------------------
// Wave = one (node, batch); batch = blockIdx.x & 7 pins each batch's 2.56MB
// hw slice to one XCD's L2. Edge walk is wave-uniform scalar (readfirstlane
// -> SGPR src, SALU addressing). CSR buckets padded to x8 -> no bounds
// logic. Software-pipelined: next 8 csr entries prefetched (named regs)
// while the current 8 gathers+FMAs execute -> one exposed L2 latency level.
__global__ __launch_bounds__(256) void agg_gru_k(const ushort_* __restrict__ hw, const int* __restrict__ offsets,
                                                 const float* __restrict__ norm_in,
                                                 const int2* __restrict__ csr_ed,
                                                 const float* __restrict__ gcn_b,
                                                 const float* __restrict__ xr, const float* __restrict__ xz,
                                                 const float* __restrict__ xh,
                                                 const float* __restrict__ h_prev, float* __restrict__ out) {
    const int lane = threadIdx.x & 63;
    const int wave = threadIdx.x >> 6;
    const int b  = blockIdx.x & 7;                  // XCD-pinned batch
    const int ng = blockIdx.x >> 3;                 // node group (0..2499)
    const int n  = ng * 4 + wave;
    const int o  = __builtin_amdgcn_readfirstlane(offsets[n]);
    const int dc = __builtin_amdgcn_readfirstlane(offsets[n + 1]) - o;   // multiple of 8
    const int2* __restrict__ ed = csr_ed + o;
    const ushort_* __restrict__ hb = hw + (size_t)b * (N_ * H_) + lane * 2;

    // hoisted epilogue operands (latency overlaps the gather walk)
    const float ni = norm_in[n];
    const int col = lane * 2;
    const size_t off = ((size_t)b * N_ + n) * H_ + col;
    float2 hp = *(const float2*)(h_prev + off);
    float2 gb = *(const float2*)(gcn_b + col);
    float2 vr = *(const float2*)(xr + b * H_ + col);
    float2 vz = *(const float2*)(xz + b * H_ + col);
    float2 vh = *(const float2*)(xh + b * H_ + col);

    float a0 = 0.f, a1 = 0.f;
    if (dc > 0) {
        int2 c0 = ed[0], c1 = ed[1], c2 = ed[2], c3 = ed[3];
        int2 c4 = ed[4], c5 = ed[5], c6 = ed[6], c7 = ed[7];
        for (int j = 8; j < dc; j += 8) {
            int2 p0 = ed[j + 0], p1 = ed[j + 1], p2 = ed[j + 2], p3 = ed[j + 3];
            int2 p4 = ed[j + 4], p5 = ed[j + 5], p6 = ed[j + 6], p7 = ed[j + 7];
            PROC_(c0); PROC_(c1); PROC_(c2); PROC_(c3);
            PROC_(c4); PROC_(c5); PROC_(c6); PROC_(c7);
            c0 = p0; c1 = p1; c2 = p2; c3 = p3;
            c4 = p4; c5 = p5; c6 = p6; c7 = p7;
        }
        PROC_(c0); PROC_(c1); PROC_(c2); PROC_(c3);
        PROC_(c4); PROC_(c5); PROC_(c6); PROC_(c7);
    }

    float2 wv;
    {
        float hc = a0 * ni + gb.x;
        float rr = sigmoidf_(vr.x + hc);
        float zz = sigmoidf_(vz.x + hc);
        float ht = tanh_fast(vh.x + rr * hc);
        wv.x = (1.f - zz) * hp.x + zz * ht;
    }
    {
        float hc = a1 * ni + gb.y;
        float rr = sigmoidf_(vr.y + hc);
        float zz = sigmoidf_(vz.y + hc);
        float ht = tanh_fast(vh.y + rr * hc);
        wv.y = (1.f - zz) * hp.y + zz * ht;
    }
    *(float2*)(out + off) = wv;
}

extern "C" void kernel_launch(void* const* d_in, const int* in_sizes, int n_in,
                              void* d_out, int out_size, void* d_ws, size_t ws_size,
                              hipStream_t stream) {
    (void)in_sizes; (void)n_in; (void)out_size; (void)ws_size;
    const float* x      = (const float*)d_in[0];
    const float* h_prev = (const float*)d_in[1];
    const int*   src    = (const int*)d_in[2];
    const int*   dst    = (const int*)d_in[3];
    const float* w_r    = (const float*)d_in[4];
    const float* b_r    = (const float*)d_in[5];
    const float* w_z    = (const float*)d_in[6];
    const float* b_z    = (const float*)d_in[7];
    const float* w_h    = (const float*)d_in[8];
    const float* b_h    = (const float*)d_in[9];
    const float* gcn_w  = (const float*)d_in[10];
    const float* gcn_b  = (const float*)d_in[11];
    float* out = (float*)d_out;

    ushort_* hw = (ushort_*)d_ws;                  // B*N*H bf16 = 20.48 MB
    int* wsi = (int*)(hw + (size_t)B_ * N_ * H_);
    int* out_deg   = wsi;                          // N
    int* in_deg    = wsi + N_;                     // N
    int* cursor    = wsi + 2 * N_;                 // N
    int2* csr_ed   = (int2*)(wsi + 3 * N_);        // EPAD_ packed (src, coef)
    int* offsets   = (int*)(csr_ed + EPAD_);       // N+1
    float* norm_out = (float*)(offsets + N_ + 1);  // N
    float* norm_in  = norm_out + N_;               // N
    float* xr = norm_in + N_;                      // B*H
    float* xz = xr + B_ * H_;
    float* xh = xz + B_ * H_;
    ushort_* wt = (ushort_*)(xh + B_ * H_);        // H*H bf16 = 32 KB

    // zero out_deg, in_deg, cursor AND the padded CSR (pad slots: src=0, coef=0)
    hipMemsetAsync(out_deg, 0, 3 * N_ * sizeof(int) + EPAD_ * sizeof(int2), stream);
    degrees_k<<<(E_ + 255) / 256, 256, 0, stream>>>(src, dst, out_deg, in_deg);
    norms_scan_k<<<1, 1024, 0, stream>>>(out_deg, in_deg, norm_out, norm_in, offsets);
    fill_csr_k<<<(E_ + 255) / 256, 256, 0, stream>>>(src, dst, offsets, cursor, norm_out, csr_ed);
    xproj_k<<<dim3(4, B_), 256, 0, stream>>>(x, w_r, b_r, w_z, b_z, w_h, b_h, gcn_w, wt, xr, xz, xh);
    gemm_cast_k<<<dim3(8, 79), 512, 0, stream>>>(h_prev, wt, hw);
    agg_gru_k<<<(N_ / 4) * 8, 256, 0, stream>>>(hw, offsets, norm_in, csr_ed,
                                                gcn_b, xr, xz, xh, h_prev, out);
}